// Round 17
// baseline (407.596 us; speedup 1.0000x reference)
//
#include <hip/hip_runtime.h>
#include <math.h>

#define NN    100000
#define INF_  256
#define HID   128
#define OUTF  16
#define NE    1600000
#define BUK   256
#define NBUK  ((NN + BUK - 1) / BUK)      // 391
#define NB_F  128                          // fill blocks
#define EPB_F (NE / NB_F)                  // 12500
#define NB2   (NBUK * NB_F)                // 50048
#define WPREP_B 128
#define GEMM_B ((NN + 127) / 128)          // 782
#define NRANGE ((NN + 63) / 64)            // 1563 blocks of 64 nodes

typedef __attribute__((ext_vector_type(4))) float f32x4;
typedef __attribute__((ext_vector_type(8))) short bf16x8;

__device__ inline unsigned short f32_to_bf16(float f) {
  union { float f; unsigned int u; } v; v.f = f;
  unsigned int x = v.u;
  unsigned int r = x + 0x7fffu + ((x >> 16) & 1u);  // RNE
  return (unsigned short)(r >> 16);
}

// accumulate 8 fp8 channels from uint2 u into acc[0..7] (literal selectors required)
#define ACC_FP8(u, acc) do { \
  acc[0] += __builtin_amdgcn_cvt_f32_fp8((u).x, 0); \
  acc[1] += __builtin_amdgcn_cvt_f32_fp8((u).x, 1); \
  acc[2] += __builtin_amdgcn_cvt_f32_fp8((u).x, 2); \
  acc[3] += __builtin_amdgcn_cvt_f32_fp8((u).x, 3); \
  acc[4] += __builtin_amdgcn_cvt_f32_fp8((u).y, 0); \
  acc[5] += __builtin_amdgcn_cvt_f32_fp8((u).y, 1); \
  acc[6] += __builtin_amdgcn_cvt_f32_fp8((u).y, 2); \
  acc[7] += __builtin_amdgcn_cvt_f32_fp8((u).y, 3); \
} while (0)

// channel map for slice-packed layout: c_lin = s*32 + g*4 + k  ->  true channel
__device__ inline int chmap(int c_lin) {
  const int s = c_lin >> 5, g = (c_lin >> 2) & 7, k = c_lin & 3;
  const int kk = (k == 0) ? 0 : (k == 1) ? 16 : (k == 2) ? 1 : 17;
  return 32 * s + 2 * g + kk;
}

// ---------------------------------------------------------------- pre: hist2d (blocks 0..127) + wprep (blocks 128..255)
__global__ __launch_bounds__(256) void k_pre(const int* __restrict__ dst,
                                             int* __restrict__ H,
                                             const float* __restrict__ W,
                                             unsigned short* __restrict__ WTs) {
  __shared__ int lh[NBUK];
  const int t = threadIdx.x;
  if (blockIdx.x < NB_F) {
    const int b = blockIdx.x;
    for (int i = t; i < NBUK; i += 256) lh[i] = 0;
    __syncthreads();
    const int beg = b * EPB_F;
    for (int i = beg + t; i < beg + EPB_F; i += 256) atomicAdd(&lh[dst[i] >> 8], 1);
    __syncthreads();
    for (int i = t; i < NBUK; i += 256) H[i * NB_F + b] = lh[i];
  } else {
    const int i = (blockIdx.x - NB_F) * 256 + t;
    if (i < INF_ * HID) {
      const int k = i >> 7, n = i & 127;
      const int s = k >> 5, c = (k >> 3) & 3, j = k & 7;
      const int chunk = s * 512 + n * 4 + (c ^ (n & 3));
      WTs[chunk * 8 + j] = f32_to_bf16(W[i]);
    }
  }
}

// ---------------------------------------------------------------- fillb: self-computed prefixes, then scatter
__global__ __launch_bounds__(256) void k_fillb(const int* __restrict__ src,
                                               const int* __restrict__ dst,
                                               const int* __restrict__ H,
                                               int* __restrict__ gB,
                                               unsigned int* __restrict__ binned) {
  __shared__ int lbase[NBUK];
  __shared__ int lcnt[NBUK];
  __shared__ int tot[NBUK];
  __shared__ int bb[NBUK + 1];
  __shared__ int sh[256];
  const int t = threadIdx.x;
  const int myblk = blockIdx.x;

#pragma unroll
  for (int rr = 0; rr < 2; ++rr) {
    const int i = t + rr * 256;
    if (i < NBUK) {
      const int* row = &H[i * NB_F];
      int pre = 0, tt = 0;
      for (int k = 0; k < NB_F; ++k) {
        const int h = row[k];
        tt += h;
        if (k < myblk) pre += h;
      }
      tot[i] = tt; lbase[i] = pre; lcnt[i] = 0;
    }
  }
  __syncthreads();
  const int i0 = 2 * t, i1 = 2 * t + 1;
  const int va = (i0 < NBUK) ? tot[i0] : 0;
  const int vb = (i1 < NBUK) ? tot[i1] : 0;
  sh[t] = va + vb;
  __syncthreads();
  for (int off = 1; off < 256; off <<= 1) {
    int tmp = (t >= off) ? sh[t - off] : 0;
    __syncthreads();
    sh[t] += tmp;
    __syncthreads();
  }
  int run = (t > 0) ? sh[t - 1] : 0;
  if (i0 < NBUK) bb[i0] = run;
  if (i1 < NBUK) bb[i1] = run + va;
  if (t == 255) bb[NBUK] = run + va + vb;  // == NE
  __syncthreads();
#pragma unroll
  for (int rr = 0; rr < 2; ++rr) {
    const int i = t + rr * 256;
    if (i < NBUK) {
      lbase[i] += bb[i];
      if (myblk == 0) gB[i] = bb[i];
    }
  }
  if (myblk == 0 && t == 0) gB[NBUK] = bb[NBUK];
  __syncthreads();

  const int beg = myblk * EPB_F;
#pragma unroll 4
  for (int i = beg + t; i < beg + EPB_F; i += 256) {
    const int d = dst[i];
    const int b = d >> 8;
    const unsigned w = ((unsigned)src[i] << 8) | (unsigned)(d & 255);
    const int pos = atomicAdd(&lcnt[b], 1);
    binned[lbase[b] + pos] = w;
  }
}

// ---------------------------------------------------------------- per-bucket: hist -> rowptr/dinv, then csr scatter
__global__ __launch_bounds__(256) void k_csr(const unsigned int* __restrict__ binned,
                                             const int* __restrict__ gB,
                                             int* __restrict__ rowptr,
                                             float* __restrict__ dinv,
                                             int* __restrict__ csr) {
  __shared__ int hist[BUK];
  __shared__ int sh[256];
  __shared__ int lcur[BUK];
  const int b = blockIdx.x, t = threadIdx.x;
  hist[t] = 0;
  __syncthreads();
  const int e0 = gB[b], e1 = gB[b + 1];
  for (int i = e0 + t; i < e1; i += 256) atomicAdd(&hist[binned[i] & 255u], 1);
  __syncthreads();
  const int hv = hist[t];
  sh[t] = hv;
  __syncthreads();
  for (int off = 1; off < 256; off <<= 1) {
    int tmp = (t >= off) ? sh[t - off] : 0;
    __syncthreads();
    sh[t] += tmp;
    __syncthreads();
  }
  const int excl = sh[t] - hv;
  lcur[t] = excl;
  const int nid = b * BUK + t;
  if (nid < NN) {
    rowptr[nid] = e0 + excl;
    dinv[nid] = rsqrtf((float)(hv + 1));
  }
  if (b == NBUK - 1 && t == 0) rowptr[NN] = e1;  // == NE
  __syncthreads();
  for (int i = e0 + t; i < e1; i += 256) {
    const unsigned w = binned[i];
    const int pos = atomicAdd(&lcur[w & 255u], 1);
    csr[e0 + pos] = (int)(w >> 8);
  }
}

// ---------------------------------------------------------------- MFMA GEMM -> slice-major fp8
// slice s, node v: 16 ushorts; ushort m = fp8(ch 32s+m) | fp8(ch 32s+16+m)<<8
__global__ __launch_bounds__(256) void k_gemm(const float* __restrict__ x,
                                              const unsigned short* __restrict__ WTs,
                                              const float* __restrict__ dinv,
                                              unsigned short* __restrict__ h8q) {
  __shared__ unsigned short xs[128 * 32];
  __shared__ unsigned short ws[128 * 32];
  const int tid = threadIdx.x;
  const int wave = tid >> 6, lane = tid & 63;
  const int l15 = lane & 15, l4 = lane >> 4;
  const int row0 = blockIdx.x * 128;

  f32x4 acc[2][8];
#pragma unroll
  for (int rb = 0; rb < 2; ++rb)
#pragma unroll
    for (int n = 0; n < 8; ++n) { acc[rb][n].x = 0.f; acc[rb][n].y = 0.f; acc[rb][n].z = 0.f; acc[rb][n].w = 0.f; }

  for (int s = 0; s < 8; ++s) {
#pragma unroll
    for (int p = 0; p < 2; ++p) {
      const int c = tid + p * 256;
      const int row = c >> 2, kc = c & 3;
      const int grow = row0 + row;
      unsigned short tmp[8];
      if (grow < NN) {
        const float4 v0 = *(const float4*)&x[(size_t)grow * INF_ + s * 32 + kc * 8];
        const float4 v1 = *(const float4*)&x[(size_t)grow * INF_ + s * 32 + kc * 8 + 4];
        tmp[0] = f32_to_bf16(v0.x); tmp[1] = f32_to_bf16(v0.y);
        tmp[2] = f32_to_bf16(v0.z); tmp[3] = f32_to_bf16(v0.w);
        tmp[4] = f32_to_bf16(v1.x); tmp[5] = f32_to_bf16(v1.y);
        tmp[6] = f32_to_bf16(v1.z); tmp[7] = f32_to_bf16(v1.w);
      } else {
#pragma unroll
        for (int j = 0; j < 8; ++j) tmp[j] = 0;
      }
      const int phys = kc ^ (row & 3);
      *(bf16x8*)&xs[(row * 4 + phys) * 8] = *(bf16x8*)tmp;
    }
#pragma unroll
    for (int p = 0; p < 2; ++p) {
      const int c = tid + p * 256;
      *(bf16x8*)&ws[c * 8] = *(const bf16x8*)&WTs[(s * 512 + c) * 8];
    }
    __syncthreads();
    bf16x8 af[2];
#pragma unroll
    for (int rb = 0; rb < 2; ++rb) {
      const int row = wave * 32 + rb * 16 + l15;
      af[rb] = *(const bf16x8*)&xs[(row * 4 + (l4 ^ (row & 3))) * 8];
    }
#pragma unroll
    for (int n = 0; n < 8; ++n) {
      const int col = n * 16 + l15;
      const bf16x8 bf = *(const bf16x8*)&ws[(col * 4 + (l4 ^ (col & 3))) * 8];
      acc[0][n] = __builtin_amdgcn_mfma_f32_16x16x32_bf16(af[0], bf, acc[0][n], 0, 0, 0);
      acc[1][n] = __builtin_amdgcn_mfma_f32_16x16x32_bf16(af[1], bf, acc[1][n], 0, 0, 0);
    }
    __syncthreads();
  }
#pragma unroll
  for (int rb = 0; rb < 2; ++rb) {
#pragma unroll
    for (int r = 0; r < 4; ++r) {
      const int rowg = row0 + wave * 32 + rb * 16 + l4 * 4 + r;
      if (rowg < NN) {
        const float dv = dinv[rowg];
        float vv[8];
#pragma unroll
        for (int n = 0; n < 8; ++n) vv[n] = acc[rb][n][r] * dv;  // vv[n] = channel 16n+l15
#pragma unroll
        for (int s2 = 0; s2 < 4; ++s2) {
          const int aa = __builtin_amdgcn_cvt_pk_fp8_f32(vv[2 * s2], vv[2 * s2 + 1], 0, false);
          h8q[(size_t)s2 * NN * 16 + (size_t)rowg * 16 + l15] = (unsigned short)aa;
        }
      }
    }
  }
}

// ---------------------------------------------------------------- gath2: block = 64 dst nodes x 4 waves(=slices), LDS accumulate + fused finalize
// wave w = slice w; lane: eg=lane>>2 (16 edge slots), sub=lane&3 (8 channels each)
__global__ __launch_bounds__(256) void k_gath2(const int* __restrict__ rowptr,
                                               const int* __restrict__ csr,
                                               const unsigned int* __restrict__ h8q,
                                               const float* __restrict__ dinv,
                                               const float* __restrict__ bc,
                                               const float* __restrict__ Wl,
                                               const float* __restrict__ bl,
                                               float* __restrict__ out) {
  __shared__ float tL[64 * 132];    // 33.8 KB raw slice sums (c_lin order)
  __shared__ float WlL[HID * OUTF]; // 8 KB, remapped
  __shared__ float bcL[HID];
  __shared__ float blL[OUTF];
  const int t = threadIdx.x;
  const int w = t >> 6, lane = t & 63;
  const int eg = lane >> 2, sub = lane & 3;
  const int v0 = blockIdx.x * 64;

  // init remapped Wl/bc/bl
  {
    const int c = t >> 1, half = (t & 1) * 8;
    const int mc = chmap(c);
    const float4* srcw = (const float4*)&Wl[(size_t)mc * OUTF + half];
    float4* dstw = (float4*)&WlL[c * OUTF + half];
    dstw[0] = srcw[0];
    dstw[1] = srcw[1];
  }
  if (t < HID) bcL[t] = bc[chmap(t)];
  if (t < OUTF) blL[t] = bl[t];
  __syncthreads();

  const unsigned* hs = h8q + (size_t)w * NN * 8;  // dword view of my slice (3.2 MB)

  // ---- accumulate: wave sweeps its slice for all 64 nodes
  for (int i = 0; i < 64; ++i) {
    const int v = v0 + i;
    if (v >= NN) break;  // uniform across block
    const int rp = __builtin_amdgcn_readfirstlane(rowptr[v]);
    const int re = __builtin_amdgcn_readfirstlane(rowptr[v + 1]);
    float acc[8];
#pragma unroll
    for (int q = 0; q < 8; ++q) acc[q] = 0.f;

    for (int base = rp; base < re; base += 16) {
      const int slot = base + eg;
      if (slot < re) {
        const int srcv = csr[slot];
        const uint2 u = *(const uint2*)&hs[(size_t)srcv * 8 + sub * 2];
        ACC_FP8(u, acc);
      }
    }
    // reduce over the 16 edge slots (lane stride 4)
#pragma unroll
    for (int q = 0; q < 8; ++q) {
      acc[q] += __shfl_xor(acc[q], 4);
      acc[q] += __shfl_xor(acc[q], 8);
      acc[q] += __shfl_xor(acc[q], 16);
      acc[q] += __shfl_xor(acc[q], 32);
    }
    if (eg == 0) {
      // self-loop (fp8 slice row), added once
      const uint2 u = *(const uint2*)&hs[(size_t)v * 8 + sub * 2];
      ACC_FP8(u, acc);
      f32x4 o0, o1;
      o0.x = acc[0]; o0.y = acc[1]; o0.z = acc[2]; o0.w = acc[3];
      o1.x = acc[4]; o1.y = acc[5]; o1.z = acc[6]; o1.w = acc[7];
      *(f32x4*)&tL[i * 132 + 32 * w + 8 * sub] = o0;
      *(f32x4*)&tL[i * 132 + 32 * w + 8 * sub + 4] = o1;
    }
  }
  __syncthreads();

  // ---- finalize: 4 lanes per node, 4 outputs per lane
  const int nl = t >> 2, q = t & 3;
  const int v = v0 + nl;
  const float dv = (v < NN) ? dinv[v] : 0.f;
  const float* tp = &tL[nl * 132];
  float a0 = 0.f, a1 = 0.f, a2 = 0.f, a3 = 0.f;
#pragma unroll 8
  for (int c = 0; c < HID; ++c) {
    const float tc = fmaxf(fmaf(dv, tp[c], bcL[c]), 0.f);
    const float4 w4 = *(const float4*)&WlL[c * OUTF + 4 * q];
    a0 = fmaf(tc, w4.x, a0);
    a1 = fmaf(tc, w4.y, a1);
    a2 = fmaf(tc, w4.z, a2);
    a3 = fmaf(tc, w4.w, a3);
  }
  a0 += blL[4 * q + 0]; a1 += blL[4 * q + 1]; a2 += blL[4 * q + 2]; a3 += blL[4 * q + 3];
  float mx = fmaxf(fmaxf(a0, a1), fmaxf(a2, a3));
  mx = fmaxf(mx, __shfl_xor(mx, 1));
  mx = fmaxf(mx, __shfl_xor(mx, 2));
  float se = expf(a0 - mx) + expf(a1 - mx) + expf(a2 - mx) + expf(a3 - mx);
  se += __shfl_xor(se, 1);
  se += __shfl_xor(se, 2);
  const float lse = mx + logf(se);
  if (v < NN) {
    float4 o4;
    o4.x = a0 - lse; o4.y = a1 - lse; o4.z = a2 - lse; o4.w = a3 - lse;
    *(float4*)&out[(size_t)v * OUTF + 4 * q] = o4;
  }
}

// ---------------------------------------------------------------- launch
extern "C" void kernel_launch(void* const* d_in, const int* in_sizes, int n_in,
                              void* d_out, int out_size, void* d_ws, size_t ws_size,
                              hipStream_t stream) {
  const float* x  = (const float*)d_in[0];
  const int*   ei = (const int*)d_in[1];
  const float* Wc = (const float*)d_in[2];
  const float* bc = (const float*)d_in[3];
  const float* Wl = (const float*)d_in[4];
  const float* bl = (const float*)d_in[5];
  float* out = (float*)d_out;

  unsigned short* WTs = (unsigned short*)d_ws;              // 64 KB
  float* dinv   = (float*)(WTs + (size_t)INF_ * HID);       // NN f32
  int*   rowptr = (int*)(dinv + NN);                        // NN+1
  int*   H      = rowptr + NN + 1;                          // NB2
  int*   gB     = H + NB2;                                  // NBUK+1
  unsigned int* binned = (unsigned int*)(gB + NBUK + 1);    // NE
  int*   csr    = (int*)(binned + NE);                      // NE
  unsigned short* h8q = (unsigned short*)(csr + NE);        // 4*NN*16 ushort = 12.8 MB

  const int* srcv = ei;
  const int* dstv = ei + NE;

  k_pre<<<NB_F + WPREP_B, 256, 0, stream>>>(dstv, H, Wc, WTs);
  k_fillb<<<NB_F, 256, 0, stream>>>(srcv, dstv, H, gB, binned);
  k_csr<<<NBUK, 256, 0, stream>>>(binned, gB, rowptr, dinv, csr);
  k_gemm<<<GEMM_B, 256, 0, stream>>>(x, WTs, dinv, h8q);
  k_gath2<<<NRANGE, 256, 0, stream>>>(rowptr, csr, (const unsigned int*)h8q,
                                      dinv, bc, Wl, bl, out);
}

// Round 18
// 185.064 us; speedup vs baseline: 2.2025x; 2.2025x over previous
//
#include <hip/hip_runtime.h>
#include <math.h>

#define NN    100000
#define INF_  256
#define HID   128
#define OUTF  16
#define NE    1600000
#define BUK   256
#define NBUK  ((NN + BUK - 1) / BUK)      // 391
#define NB_F  128                          // fill blocks
#define EPB_F (NE / NB_F)                  // 12500
#define NB2   (NBUK * NB_F)                // 50048
#define WPREP_B 128
#define GEMM_B ((NN + 127) / 128)          // 782
#define GBLK  3125
#define NPW   8                            // nodes per wave (3125*4*8 = 100000)

typedef __attribute__((ext_vector_type(4))) float f32x4;
typedef __attribute__((ext_vector_type(8))) short bf16x8;

__device__ inline unsigned short f32_to_bf16(float f) {
  union { float f; unsigned int u; } v; v.f = f;
  unsigned int x = v.u;
  unsigned int r = x + 0x7fffu + ((x >> 16) & 1u);  // RNE
  return (unsigned short)(r >> 16);
}

// accumulate 8 fp8 channels from uint2 u into acc[0..7] (literal selectors required)
#define ACC_FP8(u, acc) do { \
  acc[0] += __builtin_amdgcn_cvt_f32_fp8((u).x, 0); \
  acc[1] += __builtin_amdgcn_cvt_f32_fp8((u).x, 1); \
  acc[2] += __builtin_amdgcn_cvt_f32_fp8((u).x, 2); \
  acc[3] += __builtin_amdgcn_cvt_f32_fp8((u).x, 3); \
  acc[4] += __builtin_amdgcn_cvt_f32_fp8((u).y, 0); \
  acc[5] += __builtin_amdgcn_cvt_f32_fp8((u).y, 1); \
  acc[6] += __builtin_amdgcn_cvt_f32_fp8((u).y, 2); \
  acc[7] += __builtin_amdgcn_cvt_f32_fp8((u).y, 3); \
} while (0)

// ---------------------------------------------------------------- pre: hist2d (blocks 0..127) + wprep (blocks 128..255)
__global__ __launch_bounds__(256) void k_pre(const int* __restrict__ dst,
                                             int* __restrict__ H,
                                             const float* __restrict__ W,
                                             unsigned short* __restrict__ WTs) {
  __shared__ int lh[NBUK];
  const int t = threadIdx.x;
  if (blockIdx.x < NB_F) {
    const int b = blockIdx.x;
    for (int i = t; i < NBUK; i += 256) lh[i] = 0;
    __syncthreads();
    const int beg = b * EPB_F;
    for (int i = beg + t; i < beg + EPB_F; i += 256) atomicAdd(&lh[dst[i] >> 8], 1);
    __syncthreads();
    for (int i = t; i < NBUK; i += 256) H[i * NB_F + b] = lh[i];
  } else {
    const int i = (blockIdx.x - NB_F) * 256 + t;
    if (i < INF_ * HID) {
      const int k = i >> 7, n = i & 127;
      const int s = k >> 5, c = (k >> 3) & 3, j = k & 7;
      const int chunk = s * 512 + n * 4 + (c ^ (n & 3));
      WTs[chunk * 8 + j] = f32_to_bf16(W[i]);
    }
  }
}

// ---------------------------------------------------------------- fillb: self-computed prefixes, then scatter
__global__ __launch_bounds__(256) void k_fillb(const int* __restrict__ src,
                                               const int* __restrict__ dst,
                                               const int* __restrict__ H,
                                               int* __restrict__ gB,
                                               unsigned int* __restrict__ binned) {
  __shared__ int lbase[NBUK];
  __shared__ int lcnt[NBUK];
  __shared__ int tot[NBUK];
  __shared__ int bb[NBUK + 1];
  __shared__ int sh[256];
  const int t = threadIdx.x;
  const int myblk = blockIdx.x;

#pragma unroll
  for (int rr = 0; rr < 2; ++rr) {
    const int i = t + rr * 256;
    if (i < NBUK) {
      const int* row = &H[i * NB_F];
      int pre = 0, tt = 0;
      for (int k = 0; k < NB_F; ++k) {
        const int h = row[k];
        tt += h;
        if (k < myblk) pre += h;
      }
      tot[i] = tt; lbase[i] = pre; lcnt[i] = 0;
    }
  }
  __syncthreads();
  const int i0 = 2 * t, i1 = 2 * t + 1;
  const int va = (i0 < NBUK) ? tot[i0] : 0;
  const int vb = (i1 < NBUK) ? tot[i1] : 0;
  sh[t] = va + vb;
  __syncthreads();
  for (int off = 1; off < 256; off <<= 1) {
    int tmp = (t >= off) ? sh[t - off] : 0;
    __syncthreads();
    sh[t] += tmp;
    __syncthreads();
  }
  int run = (t > 0) ? sh[t - 1] : 0;
  if (i0 < NBUK) bb[i0] = run;
  if (i1 < NBUK) bb[i1] = run + va;
  if (t == 255) bb[NBUK] = run + va + vb;  // == NE
  __syncthreads();
#pragma unroll
  for (int rr = 0; rr < 2; ++rr) {
    const int i = t + rr * 256;
    if (i < NBUK) {
      lbase[i] += bb[i];
      if (myblk == 0) gB[i] = bb[i];
    }
  }
  if (myblk == 0 && t == 0) gB[NBUK] = bb[NBUK];
  __syncthreads();

  const int beg = myblk * EPB_F;
#pragma unroll 4
  for (int i = beg + t; i < beg + EPB_F; i += 256) {
    const int d = dst[i];
    const int b = d >> 8;
    const unsigned w = ((unsigned)src[i] << 8) | (unsigned)(d & 255);
    const int pos = atomicAdd(&lcnt[b], 1);
    binned[lbase[b] + pos] = w;
  }
}

// ---------------------------------------------------------------- per-bucket: hist -> rowptr/dinv, then csr scatter
__global__ __launch_bounds__(256) void k_csr(const unsigned int* __restrict__ binned,
                                             const int* __restrict__ gB,
                                             int* __restrict__ rowptr,
                                             float* __restrict__ dinv,
                                             int* __restrict__ csr) {
  __shared__ int hist[BUK];
  __shared__ int sh[256];
  __shared__ int lcur[BUK];
  const int b = blockIdx.x, t = threadIdx.x;
  hist[t] = 0;
  __syncthreads();
  const int e0 = gB[b], e1 = gB[b + 1];
  for (int i = e0 + t; i < e1; i += 256) atomicAdd(&hist[binned[i] & 255u], 1);
  __syncthreads();
  const int hv = hist[t];
  sh[t] = hv;
  __syncthreads();
  for (int off = 1; off < 256; off <<= 1) {
    int tmp = (t >= off) ? sh[t - off] : 0;
    __syncthreads();
    sh[t] += tmp;
    __syncthreads();
  }
  const int excl = sh[t] - hv;
  lcur[t] = excl;
  const int nid = b * BUK + t;
  if (nid < NN) {
    rowptr[nid] = e0 + excl;
    dinv[nid] = rsqrtf((float)(hv + 1));
  }
  if (b == NBUK - 1 && t == 0) rowptr[NN] = e1;  // == NE
  __syncthreads();
  for (int i = e0 + t; i < e1; i += 256) {
    const unsigned w = binned[i];
    const int pos = atomicAdd(&lcur[w & 255u], 1);
    csr[e0 + pos] = (int)(w >> 8);
  }
}

// ---------------------------------------------------------------- MFMA GEMM -> fp8 n-major only
// lane l15 owns channels {16n+l15}; uint2 = fp8 pairs (ch16n+m, ch16(n+1)+m ...)
__global__ __launch_bounds__(256) void k_gemm(const float* __restrict__ x,
                                              const unsigned short* __restrict__ WTs,
                                              const float* __restrict__ dinv,
                                              uint2* __restrict__ h8) {
  __shared__ unsigned short xs[128 * 32];
  __shared__ unsigned short ws[128 * 32];
  const int tid = threadIdx.x;
  const int wave = tid >> 6, lane = tid & 63;
  const int l15 = lane & 15, l4 = lane >> 4;
  const int row0 = blockIdx.x * 128;

  f32x4 acc[2][8];
#pragma unroll
  for (int rb = 0; rb < 2; ++rb)
#pragma unroll
    for (int n = 0; n < 8; ++n) { acc[rb][n].x = 0.f; acc[rb][n].y = 0.f; acc[rb][n].z = 0.f; acc[rb][n].w = 0.f; }

  for (int s = 0; s < 8; ++s) {
#pragma unroll
    for (int p = 0; p < 2; ++p) {
      const int c = tid + p * 256;
      const int row = c >> 2, kc = c & 3;
      const int grow = row0 + row;
      unsigned short tmp[8];
      if (grow < NN) {
        const float4 v0 = *(const float4*)&x[(size_t)grow * INF_ + s * 32 + kc * 8];
        const float4 v1 = *(const float4*)&x[(size_t)grow * INF_ + s * 32 + kc * 8 + 4];
        tmp[0] = f32_to_bf16(v0.x); tmp[1] = f32_to_bf16(v0.y);
        tmp[2] = f32_to_bf16(v0.z); tmp[3] = f32_to_bf16(v0.w);
        tmp[4] = f32_to_bf16(v1.x); tmp[5] = f32_to_bf16(v1.y);
        tmp[6] = f32_to_bf16(v1.z); tmp[7] = f32_to_bf16(v1.w);
      } else {
#pragma unroll
        for (int j = 0; j < 8; ++j) tmp[j] = 0;
      }
      const int phys = kc ^ (row & 3);
      *(bf16x8*)&xs[(row * 4 + phys) * 8] = *(bf16x8*)tmp;
    }
#pragma unroll
    for (int p = 0; p < 2; ++p) {
      const int c = tid + p * 256;
      *(bf16x8*)&ws[c * 8] = *(const bf16x8*)&WTs[(s * 512 + c) * 8];
    }
    __syncthreads();
    bf16x8 af[2];
#pragma unroll
    for (int rb = 0; rb < 2; ++rb) {
      const int row = wave * 32 + rb * 16 + l15;
      af[rb] = *(const bf16x8*)&xs[(row * 4 + (l4 ^ (row & 3))) * 8];
    }
#pragma unroll
    for (int n = 0; n < 8; ++n) {
      const int col = n * 16 + l15;
      const bf16x8 bf = *(const bf16x8*)&ws[(col * 4 + (l4 ^ (col & 3))) * 8];
      acc[0][n] = __builtin_amdgcn_mfma_f32_16x16x32_bf16(af[0], bf, acc[0][n], 0, 0, 0);
      acc[1][n] = __builtin_amdgcn_mfma_f32_16x16x32_bf16(af[1], bf, acc[1][n], 0, 0, 0);
    }
    __syncthreads();
  }
#pragma unroll
  for (int rb = 0; rb < 2; ++rb) {
#pragma unroll
    for (int r = 0; r < 4; ++r) {
      const int rowg = row0 + wave * 32 + rb * 16 + l4 * 4 + r;
      if (rowg < NN) {
        const float dv = dinv[rowg];
        float vv[8];
#pragma unroll
        for (int n = 0; n < 8; ++n) vv[n] = acc[rb][n][r] * dv;  // vv[n] = channel 16n+l15
        int a0 = 0, a1 = 0;
        a0 = __builtin_amdgcn_cvt_pk_fp8_f32(vv[0], vv[1], a0, false);
        a0 = __builtin_amdgcn_cvt_pk_fp8_f32(vv[2], vv[3], a0, true);
        a1 = __builtin_amdgcn_cvt_pk_fp8_f32(vv[4], vv[5], a1, false);
        a1 = __builtin_amdgcn_cvt_pk_fp8_f32(vv[6], vv[7], a1, true);
        h8[(size_t)rowg * 16 + l15] = make_uint2((unsigned)a0, (unsigned)a1);
      }
    }
  }
}

// ---------------------------------------------------------------- gather + finalize: r12 loop structure (16+4), fp8 self-loop
// lane l: m=l&15 owns channels {16j+m}, eg=l>>4 = edge slot
__global__ __launch_bounds__(256) void k_gather(const int* __restrict__ rowptr,
                                                const int* __restrict__ csr,
                                                const uint2* __restrict__ h8p,
                                                const float* __restrict__ dinv,
                                                const float* __restrict__ bc,
                                                const float* __restrict__ Wl,
                                                const float* __restrict__ bl,
                                                float* __restrict__ out) {
  const int lane = threadIdx.x & 63;
  const int m = lane & 15, eg = lane >> 4;
  const int wid = __builtin_amdgcn_readfirstlane(blockIdx.x * 4 + (threadIdx.x >> 6));
  const int v0 = wid * NPW;
  if (v0 >= NN) return;
  const int v1 = min(v0 + NPW, NN);

  // hoist Wl rows {16r+m}, bc channels {16j+m}, bl[4eg..]
  float4 wl[8];
#pragma unroll
  for (int r = 0; r < 8; ++r) wl[r] = *(const float4*)&Wl[(size_t)(16 * r + m) * OUTF + 4 * eg];
  float bcj[8];
#pragma unroll
  for (int j = 0; j < 8; ++j) bcj[j] = bc[16 * j + m];
  const float4 bl4 = *(const float4*)&bl[4 * eg];

  for (int v = v0; v < v1; ++v) {
    const int rp = __builtin_amdgcn_readfirstlane(rowptr[v]);
    const int re = __builtin_amdgcn_readfirstlane(rowptr[v + 1]);
    float acc[8];
#pragma unroll
    for (int q = 0; q < 8; ++q) acc[q] = 0.f;

    for (int base = rp; base < re; base += 64) {
      const int nb = min(64, re - base);
      const int csrv = (base + lane < re) ? csr[base + lane] : 0;
      int o = 0;
      // main: 16 edges per iteration -> 4 independent loads in flight
      for (; o + 16 <= nb; o += 16) {
        const int s0 = __shfl(csrv, o + eg);
        const int s1 = __shfl(csrv, o + 4 + eg);
        const int s2 = __shfl(csrv, o + 8 + eg);
        const int s3 = __shfl(csrv, o + 12 + eg);
        const uint2 u0 = h8p[(size_t)s0 * 16 + m];
        const uint2 u1 = h8p[(size_t)s1 * 16 + m];
        const uint2 u2 = h8p[(size_t)s2 * 16 + m];
        const uint2 u3 = h8p[(size_t)s3 * 16 + m];
        ACC_FP8(u0, acc);
        ACC_FP8(u1, acc);
        ACC_FP8(u2, acc);
        ACC_FP8(u3, acc);
      }
      // tail: 4 edges at a time, predicated
      for (; o < nb; o += 4) {
        const int src = __shfl(csrv, o + eg);
        if (o + eg < nb) {
          const uint2 u = h8p[(size_t)src * 16 + m];
          ACC_FP8(u, acc);
        }
      }
    }
    // cross-group reduce: full sums everywhere
#pragma unroll
    for (int q = 0; q < 8; ++q) {
      acc[q] += __shfl_xor(acc[q], 16);
      acc[q] += __shfl_xor(acc[q], 32);
    }
    // self-loop (fp8) + bias + relu
    const float dv = dinv[v];
    const uint2 su = h8p[(size_t)v * 16 + m];
    ACC_FP8(su, acc);
    float t[8];
#pragma unroll
    for (int j = 0; j < 8; ++j) t[j] = fmaxf(fmaf(dv, acc[j], bcj[j]), 0.f);
    // partial logits for this group's 4 outputs
    float p0 = 0.f, p1 = 0.f, p2 = 0.f, p3 = 0.f;
#pragma unroll
    for (int r = 0; r < 8; ++r) {
      p0 = fmaf(t[r], wl[r].x, p0);
      p1 = fmaf(t[r], wl[r].y, p1);
      p2 = fmaf(t[r], wl[r].z, p2);
      p3 = fmaf(t[r], wl[r].w, p3);
    }
    // reduce over the 16 lanes of the group
#pragma unroll
    for (int off = 1; off <= 8; off <<= 1) {
      p0 += __shfl_xor(p0, off);
      p1 += __shfl_xor(p1, off);
      p2 += __shfl_xor(p2, off);
      p3 += __shfl_xor(p3, off);
    }
    p0 += bl4.x; p1 += bl4.y; p2 += bl4.z; p3 += bl4.w;
    // softmax across 16 outputs (4 per group)
    float mx = fmaxf(fmaxf(p0, p1), fmaxf(p2, p3));
    mx = fmaxf(mx, __shfl_xor(mx, 16));
    mx = fmaxf(mx, __shfl_xor(mx, 32));
    float se = expf(p0 - mx) + expf(p1 - mx) + expf(p2 - mx) + expf(p3 - mx);
    se += __shfl_xor(se, 16);
    se += __shfl_xor(se, 32);
    const float lse = mx + logf(se);
    if (m == 0) {
      float4 o4;
      o4.x = p0 - lse; o4.y = p1 - lse; o4.z = p2 - lse; o4.w = p3 - lse;
      *(float4*)&out[(size_t)v * OUTF + 4 * eg] = o4;
    }
  }
}

// ---------------------------------------------------------------- launch
extern "C" void kernel_launch(void* const* d_in, const int* in_sizes, int n_in,
                              void* d_out, int out_size, void* d_ws, size_t ws_size,
                              hipStream_t stream) {
  const float* x  = (const float*)d_in[0];
  const int*   ei = (const int*)d_in[1];
  const float* Wc = (const float*)d_in[2];
  const float* bc = (const float*)d_in[3];
  const float* Wl = (const float*)d_in[4];
  const float* bl = (const float*)d_in[5];
  float* out = (float*)d_out;

  unsigned short* WTs = (unsigned short*)d_ws;              // 64 KB
  float* dinv   = (float*)(WTs + (size_t)INF_ * HID);       // NN f32
  int*   rowptr = (int*)(dinv + NN);                        // NN+1
  int*   H      = rowptr + NN + 1;                          // NB2
  int*   gB     = H + NB2;                                  // NBUK+1
  unsigned int* binned = (unsigned int*)(gB + NBUK + 1);    // NE
  int*   csr    = (int*)(binned + NE);                      // NE
  uint2* h8     = (uint2*)(csr + NE);                       // NN*16 uint2 = 12.8 MB

  const int* srcv = ei;
  const int* dstv = ei + NE;

  k_pre<<<NB_F + WPREP_B, 256, 0, stream>>>(dstv, H, Wc, WTs);
  k_fillb<<<NB_F, 256, 0, stream>>>(srcv, dstv, H, gB, binned);
  k_csr<<<NBUK, 256, 0, stream>>>(binned, gB, rowptr, dinv, csr);
  k_gemm<<<GEMM_B, 256, 0, stream>>>(x, WTs, dinv, h8);
  k_gather<<<GBLK, 256, 0, stream>>>(rowptr, csr, h8, dinv, bc, Wl, bl, out);
}

// Round 19
// 183.795 us; speedup vs baseline: 2.2177x; 1.0069x over previous
//
#include <hip/hip_runtime.h>
#include <math.h>

#define NN    100000
#define INF_  256
#define HID   128
#define OUTF  16
#define NE    1600000
#define BUK   256
#define NBUK  ((NN + BUK - 1) / BUK)      // 391
#define NB_F  128                          // fill blocks
#define EPB_F (NE / NB_F)                  // 12500
#define NB2   (NBUK * NB_F)                // 50048
#define WPREP_B 128
#define GEMM_B ((NN + 127) / 128)          // 782
#define GBLK  3125
#define NPW   8                            // nodes per wave (3125*4*8 = 100000)

typedef __attribute__((ext_vector_type(4))) float f32x4;
typedef __attribute__((ext_vector_type(2))) float f32x2;
typedef __attribute__((ext_vector_type(8))) short bf16x8;

__device__ inline unsigned short f32_to_bf16(float f) {
  union { float f; unsigned int u; } v; v.f = f;
  unsigned int x = v.u;
  unsigned int r = x + 0x7fffu + ((x >> 16) & 1u);  // RNE
  return (unsigned short)(r >> 16);
}

// accumulate 8 fp8 channels from uint2 u into acc[0..7] via packed converts
#define ACC_FP8(u, acc) do { \
  const f32x2 c0 = __builtin_amdgcn_cvt_pk_f32_fp8((u).x, false); \
  const f32x2 c1 = __builtin_amdgcn_cvt_pk_f32_fp8((u).x, true); \
  const f32x2 c2 = __builtin_amdgcn_cvt_pk_f32_fp8((u).y, false); \
  const f32x2 c3 = __builtin_amdgcn_cvt_pk_f32_fp8((u).y, true); \
  acc[0] += c0.x; acc[1] += c0.y; \
  acc[2] += c1.x; acc[3] += c1.y; \
  acc[4] += c2.x; acc[5] += c2.y; \
  acc[6] += c3.x; acc[7] += c3.y; \
} while (0)

// ---------------------------------------------------------------- pre: hist2d (blocks 0..127) + wprep (blocks 128..255)
__global__ __launch_bounds__(256) void k_pre(const int* __restrict__ dst,
                                             int* __restrict__ H,
                                             const float* __restrict__ W,
                                             unsigned short* __restrict__ WTs) {
  __shared__ int lh[NBUK];
  const int t = threadIdx.x;
  if (blockIdx.x < NB_F) {
    const int b = blockIdx.x;
    for (int i = t; i < NBUK; i += 256) lh[i] = 0;
    __syncthreads();
    const int beg = b * EPB_F;
    for (int i = beg + t; i < beg + EPB_F; i += 256) atomicAdd(&lh[dst[i] >> 8], 1);
    __syncthreads();
    for (int i = t; i < NBUK; i += 256) H[i * NB_F + b] = lh[i];
  } else {
    const int i = (blockIdx.x - NB_F) * 256 + t;
    if (i < INF_ * HID) {
      const int k = i >> 7, n = i & 127;
      const int s = k >> 5, c = (k >> 3) & 3, j = k & 7;
      const int chunk = s * 512 + n * 4 + (c ^ (n & 3));
      WTs[chunk * 8 + j] = f32_to_bf16(W[i]);
    }
  }
}

// ---------------------------------------------------------------- fillb: self-computed prefixes, then scatter
__global__ __launch_bounds__(256) void k_fillb(const int* __restrict__ src,
                                               const int* __restrict__ dst,
                                               const int* __restrict__ H,
                                               int* __restrict__ gB,
                                               unsigned int* __restrict__ binned) {
  __shared__ int lbase[NBUK];
  __shared__ int lcnt[NBUK];
  __shared__ int tot[NBUK];
  __shared__ int bb[NBUK + 1];
  __shared__ int sh[256];
  const int t = threadIdx.x;
  const int myblk = blockIdx.x;

#pragma unroll
  for (int rr = 0; rr < 2; ++rr) {
    const int i = t + rr * 256;
    if (i < NBUK) {
      const int* row = &H[i * NB_F];
      int pre = 0, tt = 0;
      for (int k = 0; k < NB_F; ++k) {
        const int h = row[k];
        tt += h;
        if (k < myblk) pre += h;
      }
      tot[i] = tt; lbase[i] = pre; lcnt[i] = 0;
    }
  }
  __syncthreads();
  const int i0 = 2 * t, i1 = 2 * t + 1;
  const int va = (i0 < NBUK) ? tot[i0] : 0;
  const int vb = (i1 < NBUK) ? tot[i1] : 0;
  sh[t] = va + vb;
  __syncthreads();
  for (int off = 1; off < 256; off <<= 1) {
    int tmp = (t >= off) ? sh[t - off] : 0;
    __syncthreads();
    sh[t] += tmp;
    __syncthreads();
  }
  int run = (t > 0) ? sh[t - 1] : 0;
  if (i0 < NBUK) bb[i0] = run;
  if (i1 < NBUK) bb[i1] = run + va;
  if (t == 255) bb[NBUK] = run + va + vb;  // == NE
  __syncthreads();
#pragma unroll
  for (int rr = 0; rr < 2; ++rr) {
    const int i = t + rr * 256;
    if (i < NBUK) {
      lbase[i] += bb[i];
      if (myblk == 0) gB[i] = bb[i];
    }
  }
  if (myblk == 0 && t == 0) gB[NBUK] = bb[NBUK];
  __syncthreads();

  const int beg = myblk * EPB_F;
#pragma unroll 4
  for (int i = beg + t; i < beg + EPB_F; i += 256) {
    const int d = dst[i];
    const int b = d >> 8;
    const unsigned w = ((unsigned)src[i] << 8) | (unsigned)(d & 255);
    const int pos = atomicAdd(&lcnt[b], 1);
    binned[lbase[b] + pos] = w;
  }
}

// ---------------------------------------------------------------- per-bucket: hist -> rowptr/dinv, then csr scatter
__global__ __launch_bounds__(256) void k_csr(const unsigned int* __restrict__ binned,
                                             const int* __restrict__ gB,
                                             int* __restrict__ rowptr,
                                             float* __restrict__ dinv,
                                             int* __restrict__ csr) {
  __shared__ int hist[BUK];
  __shared__ int sh[256];
  __shared__ int lcur[BUK];
  const int b = blockIdx.x, t = threadIdx.x;
  hist[t] = 0;
  __syncthreads();
  const int e0 = gB[b], e1 = gB[b + 1];
  for (int i = e0 + t; i < e1; i += 256) atomicAdd(&hist[binned[i] & 255u], 1);
  __syncthreads();
  const int hv = hist[t];
  sh[t] = hv;
  __syncthreads();
  for (int off = 1; off < 256; off <<= 1) {
    int tmp = (t >= off) ? sh[t - off] : 0;
    __syncthreads();
    sh[t] += tmp;
    __syncthreads();
  }
  const int excl = sh[t] - hv;
  lcur[t] = excl;
  const int nid = b * BUK + t;
  if (nid < NN) {
    rowptr[nid] = e0 + excl;
    dinv[nid] = rsqrtf((float)(hv + 1));
  }
  if (b == NBUK - 1 && t == 0) rowptr[NN] = e1;  // == NE
  __syncthreads();
  for (int i = e0 + t; i < e1; i += 256) {
    const unsigned w = binned[i];
    const int pos = atomicAdd(&lcur[w & 255u], 1);
    csr[e0 + pos] = (int)(w >> 8);
  }
}

// ---------------------------------------------------------------- MFMA GEMM -> fp8 n-major only
__global__ __launch_bounds__(256) void k_gemm(const float* __restrict__ x,
                                              const unsigned short* __restrict__ WTs,
                                              const float* __restrict__ dinv,
                                              uint2* __restrict__ h8) {
  __shared__ unsigned short xs[128 * 32];
  __shared__ unsigned short ws[128 * 32];
  const int tid = threadIdx.x;
  const int wave = tid >> 6, lane = tid & 63;
  const int l15 = lane & 15, l4 = lane >> 4;
  const int row0 = blockIdx.x * 128;

  f32x4 acc[2][8];
#pragma unroll
  for (int rb = 0; rb < 2; ++rb)
#pragma unroll
    for (int n = 0; n < 8; ++n) { acc[rb][n].x = 0.f; acc[rb][n].y = 0.f; acc[rb][n].z = 0.f; acc[rb][n].w = 0.f; }

  for (int s = 0; s < 8; ++s) {
#pragma unroll
    for (int p = 0; p < 2; ++p) {
      const int c = tid + p * 256;
      const int row = c >> 2, kc = c & 3;
      const int grow = row0 + row;
      unsigned short tmp[8];
      if (grow < NN) {
        const float4 v0 = *(const float4*)&x[(size_t)grow * INF_ + s * 32 + kc * 8];
        const float4 v1 = *(const float4*)&x[(size_t)grow * INF_ + s * 32 + kc * 8 + 4];
        tmp[0] = f32_to_bf16(v0.x); tmp[1] = f32_to_bf16(v0.y);
        tmp[2] = f32_to_bf16(v0.z); tmp[3] = f32_to_bf16(v0.w);
        tmp[4] = f32_to_bf16(v1.x); tmp[5] = f32_to_bf16(v1.y);
        tmp[6] = f32_to_bf16(v1.z); tmp[7] = f32_to_bf16(v1.w);
      } else {
#pragma unroll
        for (int j = 0; j < 8; ++j) tmp[j] = 0;
      }
      const int phys = kc ^ (row & 3);
      *(bf16x8*)&xs[(row * 4 + phys) * 8] = *(bf16x8*)tmp;
    }
#pragma unroll
    for (int p = 0; p < 2; ++p) {
      const int c = tid + p * 256;
      *(bf16x8*)&ws[c * 8] = *(const bf16x8*)&WTs[(s * 512 + c) * 8];
    }
    __syncthreads();
    bf16x8 af[2];
#pragma unroll
    for (int rb = 0; rb < 2; ++rb) {
      const int row = wave * 32 + rb * 16 + l15;
      af[rb] = *(const bf16x8*)&xs[(row * 4 + (l4 ^ (row & 3))) * 8];
    }
#pragma unroll
    for (int n = 0; n < 8; ++n) {
      const int col = n * 16 + l15;
      const bf16x8 bf = *(const bf16x8*)&ws[(col * 4 + (l4 ^ (col & 3))) * 8];
      acc[0][n] = __builtin_amdgcn_mfma_f32_16x16x32_bf16(af[0], bf, acc[0][n], 0, 0, 0);
      acc[1][n] = __builtin_amdgcn_mfma_f32_16x16x32_bf16(af[1], bf, acc[1][n], 0, 0, 0);
    }
    __syncthreads();
  }
#pragma unroll
  for (int rb = 0; rb < 2; ++rb) {
#pragma unroll
    for (int r = 0; r < 4; ++r) {
      const int rowg = row0 + wave * 32 + rb * 16 + l4 * 4 + r;
      if (rowg < NN) {
        const float dv = dinv[rowg];
        float vv[8];
#pragma unroll
        for (int n = 0; n < 8; ++n) vv[n] = acc[rb][n][r] * dv;  // vv[n] = channel 16n+l15
        int a0 = 0, a1 = 0;
        a0 = __builtin_amdgcn_cvt_pk_fp8_f32(vv[0], vv[1], a0, false);
        a0 = __builtin_amdgcn_cvt_pk_fp8_f32(vv[2], vv[3], a0, true);
        a1 = __builtin_amdgcn_cvt_pk_fp8_f32(vv[4], vv[5], a1, false);
        a1 = __builtin_amdgcn_cvt_pk_fp8_f32(vv[6], vv[7], a1, true);
        h8[(size_t)rowg * 16 + l15] = make_uint2((unsigned)a0, (unsigned)a1);
      }
    }
  }
}

// ---------------------------------------------------------------- gather + finalize (pk-cvt unpack)
// lane l: m=l&15 owns channels {16j+m}, eg=l>>4 = edge slot
__global__ __launch_bounds__(256) void k_gather(const int* __restrict__ rowptr,
                                                const int* __restrict__ csr,
                                                const uint2* __restrict__ h8p,
                                                const float* __restrict__ dinv,
                                                const float* __restrict__ bc,
                                                const float* __restrict__ Wl,
                                                const float* __restrict__ bl,
                                                float* __restrict__ out) {
  const int lane = threadIdx.x & 63;
  const int m = lane & 15, eg = lane >> 4;
  const int wid = __builtin_amdgcn_readfirstlane(blockIdx.x * 4 + (threadIdx.x >> 6));
  const int v0 = wid * NPW;
  if (v0 >= NN) return;
  const int v1 = min(v0 + NPW, NN);

  float4 wl[8];
#pragma unroll
  for (int r = 0; r < 8; ++r) wl[r] = *(const float4*)&Wl[(size_t)(16 * r + m) * OUTF + 4 * eg];
  float bcj[8];
#pragma unroll
  for (int j = 0; j < 8; ++j) bcj[j] = bc[16 * j + m];
  const float4 bl4 = *(const float4*)&bl[4 * eg];

  for (int v = v0; v < v1; ++v) {
    const int rp = __builtin_amdgcn_readfirstlane(rowptr[v]);
    const int re = __builtin_amdgcn_readfirstlane(rowptr[v + 1]);
    float acc[8];
#pragma unroll
    for (int q = 0; q < 8; ++q) acc[q] = 0.f;

    for (int base = rp; base < re; base += 64) {
      const int nb = min(64, re - base);
      const int csrv = (base + lane < re) ? csr[base + lane] : 0;
      int o = 0;
      for (; o + 16 <= nb; o += 16) {
        const int s0 = __shfl(csrv, o + eg);
        const int s1 = __shfl(csrv, o + 4 + eg);
        const int s2 = __shfl(csrv, o + 8 + eg);
        const int s3 = __shfl(csrv, o + 12 + eg);
        const uint2 u0 = h8p[(size_t)s0 * 16 + m];
        const uint2 u1 = h8p[(size_t)s1 * 16 + m];
        const uint2 u2 = h8p[(size_t)s2 * 16 + m];
        const uint2 u3 = h8p[(size_t)s3 * 16 + m];
        ACC_FP8(u0, acc);
        ACC_FP8(u1, acc);
        ACC_FP8(u2, acc);
        ACC_FP8(u3, acc);
      }
      for (; o < nb; o += 4) {
        const int src = __shfl(csrv, o + eg);
        if (o + eg < nb) {
          const uint2 u = h8p[(size_t)src * 16 + m];
          ACC_FP8(u, acc);
        }
      }
    }
#pragma unroll
    for (int q = 0; q < 8; ++q) {
      acc[q] += __shfl_xor(acc[q], 16);
      acc[q] += __shfl_xor(acc[q], 32);
    }
    const float dv = dinv[v];
    const uint2 su = h8p[(size_t)v * 16 + m];
    ACC_FP8(su, acc);
    float t[8];
#pragma unroll
    for (int j = 0; j < 8; ++j) t[j] = fmaxf(fmaf(dv, acc[j], bcj[j]), 0.f);
    float p0 = 0.f, p1 = 0.f, p2 = 0.f, p3 = 0.f;
#pragma unroll
    for (int r = 0; r < 8; ++r) {
      p0 = fmaf(t[r], wl[r].x, p0);
      p1 = fmaf(t[r], wl[r].y, p1);
      p2 = fmaf(t[r], wl[r].z, p2);
      p3 = fmaf(t[r], wl[r].w, p3);
    }
#pragma unroll
    for (int off = 1; off <= 8; off <<= 1) {
      p0 += __shfl_xor(p0, off);
      p1 += __shfl_xor(p1, off);
      p2 += __shfl_xor(p2, off);
      p3 += __shfl_xor(p3, off);
    }
    p0 += bl4.x; p1 += bl4.y; p2 += bl4.z; p3 += bl4.w;
    float mx = fmaxf(fmaxf(p0, p1), fmaxf(p2, p3));
    mx = fmaxf(mx, __shfl_xor(mx, 16));
    mx = fmaxf(mx, __shfl_xor(mx, 32));
    float se = expf(p0 - mx) + expf(p1 - mx) + expf(p2 - mx) + expf(p3 - mx);
    se += __shfl_xor(se, 16);
    se += __shfl_xor(se, 32);
    const float lse = mx + logf(se);
    if (m == 0) {
      float4 o4;
      o4.x = p0 - lse; o4.y = p1 - lse; o4.z = p2 - lse; o4.w = p3 - lse;
      *(float4*)&out[(size_t)v * OUTF + 4 * eg] = o4;
    }
  }
}

// ---------------------------------------------------------------- launch
extern "C" void kernel_launch(void* const* d_in, const int* in_sizes, int n_in,
                              void* d_out, int out_size, void* d_ws, size_t ws_size,
                              hipStream_t stream) {
  const float* x  = (const float*)d_in[0];
  const int*   ei = (const int*)d_in[1];
  const float* Wc = (const float*)d_in[2];
  const float* bc = (const float*)d_in[3];
  const float* Wl = (const float*)d_in[4];
  const float* bl = (const float*)d_in[5];
  float* out = (float*)d_out;

  unsigned short* WTs = (unsigned short*)d_ws;              // 64 KB
  float* dinv   = (float*)(WTs + (size_t)INF_ * HID);       // NN f32
  int*   rowptr = (int*)(dinv + NN);                        // NN+1
  int*   H      = rowptr + NN + 1;                          // NB2
  int*   gB     = H + NB2;                                  // NBUK+1
  unsigned int* binned = (unsigned int*)(gB + NBUK + 1);    // NE
  int*   csr    = (int*)(binned + NE);                      // NE
  uint2* h8     = (uint2*)(csr + NE);                       // NN*16 uint2 = 12.8 MB

  const int* srcv = ei;
  const int* dstv = ei + NE;

  k_pre<<<NB_F + WPREP_B, 256, 0, stream>>>(dstv, H, Wc, WTs);
  k_fillb<<<NB_F, 256, 0, stream>>>(srcv, dstv, H, gB, binned);
  k_csr<<<NBUK, 256, 0, stream>>>(binned, gB, rowptr, dinv, csr);
  k_gemm<<<GEMM_B, 256, 0, stream>>>(x, WTs, dinv, h8);
  k_gather<<<GBLK, 256, 0, stream>>>(rowptr, csr, h8, dinv, bc, Wl, bl, out);
}